// Round 2
// baseline (311.303 us; speedup 1.0000x reference)
//
#include <hip/hip_runtime.h>
#include <cstdint>
#include <cstddef>

// Problem constants (B=8192, P=8192, F=256; SIGMA=1 -> denom = 2)
#define B_ROWS 8192
#define P_ROWS 8192
#define FDIM   256

// GEMM tiling (m97-ladder structure: 128x128 tile, 4 waves, 4x4 16x16x32 MFMA)
#define BM 128
#define BN 128
#define BK 64
#define NSTEP (FDIM / BK)   // 4 K-steps

typedef __bf16  bf16x8  __attribute__((ext_vector_type(8)));
typedef float   floatx4 __attribute__((ext_vector_type(4)));

// round-to-nearest-even fp32 -> bf16 (inputs are finite Gaussians, no NaN path)
__device__ __forceinline__ unsigned short f2bf(float f) {
  unsigned int u = __float_as_uint(f);
  u += 0x7fffu + ((u >> 16) & 1u);
  return (unsigned short)(u >> 16);
}

// async global->LDS, 16B per lane. LDS dest is wave-uniform base + lane*16.
__device__ __forceinline__ void async16(const void* g, void* l) {
  __builtin_amdgcn_global_load_lds(
      (const __attribute__((address_space(1))) void*)g,
      (__attribute__((address_space(3))) void*)l,
      16, 0, 0);
}

// ---------------------------------------------------------------------------
// Pre-pass: convert x / prototypes to bf16 planes in ws, compute fp32 row
// norms. 256 threads = 4 waves, one row per wave (64 lanes x float4 = 256).
// ---------------------------------------------------------------------------
__global__ void __launch_bounds__(256) prep_kernel(
    const float* __restrict__ x, const float* __restrict__ p,
    unsigned short* __restrict__ xbf, unsigned short* __restrict__ pbf,
    float* __restrict__ x2, float* __restrict__ p2) {
  const int t    = threadIdx.x;
  const int lane = t & 63;
  const int row  = blockIdx.x * 4 + (t >> 6);

  const float* src;
  unsigned short* dst;
  float* nrm;
  int r;
  if (row < B_ROWS) { src = x; dst = xbf; nrm = x2; r = row; }
  else              { src = p; dst = pbf; nrm = p2; r = row - B_ROWS; }

  const float4 v = *reinterpret_cast<const float4*>(src + (size_t)r * FDIM + lane * 4);
  float s = v.x * v.x + v.y * v.y + v.z * v.z + v.w * v.w;
  #pragma unroll
  for (int o = 32; o > 0; o >>= 1) s += __shfl_down(s, o);
  if (lane == 0) nrm[r] = s;

  ushort4 pk;
  pk.x = f2bf(v.x); pk.y = f2bf(v.y); pk.z = f2bf(v.z); pk.w = f2bf(v.w);
  *reinterpret_cast<ushort4*>(dst + (size_t)r * FDIM + lane * 4) = pk;
}

// ---------------------------------------------------------------------------
// Main kernel: C = X * P^T (both K-contiguous) with distance+exp epilogue.
//
// LDS layout: [row][8 chunks of 16B] per BK=64 K-slice. Chunk slot c of row r
// holds GLOBAL chunk (c ^ (r&7))  -> XOR swizzle (keeps global_load_lds's
// lane-ordered LDS constraint; ds_read_b128 fragment reads are bank-optimal).
//
// Epilogue: per-wave LDS transpose (16x68-float chunks, 2-way write alias =
// free, b128 reads bank-optimal) -> global_store_dwordx4, 256 B contiguous
// per row per instruction.
// ---------------------------------------------------------------------------
__global__ void __launch_bounds__(256) gauss_kernel(
    const unsigned short* __restrict__ xbf, const unsigned short* __restrict__ pbf,
    const float* __restrict__ x2, const float* __restrict__ p2,
    float* __restrict__ out) {
  __shared__ __align__(16) unsigned short lds_a[BM * BK];  // 16 KiB
  __shared__ __align__(16) unsigned short lds_b[BN * BK];  // 16 KiB

  const int t    = threadIdx.x;
  const int lane = t & 63;
  const int w    = t >> 6;        // wave 0..3
  const int wr   = w >> 1;        // wave row (0..1) -> 64-row slab of M
  const int wc   = w & 1;         // wave col (0..1) -> 64-col slab of N
  const int lm   = lane & 15;     // MFMA row/col-in-16
  const int q    = lane >> 4;     // quad 0..3
  const int sx   = lane & 7;      // swizzle xor (== row&7 for this lane's rows)

  // 8x8 supertile rasterization (64 blocks per supertile) for L2 locality:
  // working set per supertile = 8 A-panels + 8 B-panels = ~1 MB << 4 MB L2/XCD.
  const int sid = blockIdx.x >> 6;
  const int wit = blockIdx.x & 63;
  const int M0 = ((sid >> 3) * 8 + (wit >> 3)) * BM;
  const int N0 = ((sid &  7) * 8 + (wit &  7)) * BN;

  // Staging addresses: 1024 16B chunks per operand per K-step.
  // Chunk id L = issue*256 + w*64 + lane; LDS placement is exactly lane order.
  const unsigned short* aSrc[4];
  const unsigned short* bSrc[4];
  int ldsOff[4];
  #pragma unroll
  for (int I = 0; I < 4; ++I) {
    const int L = I * 256 + w * 64 + lane;
    const int r = L >> 3;
    const int c = L & 7;
    const int g = c ^ (r & 7);            // global chunk to fetch for slot c
    aSrc[I] = xbf + (size_t)(M0 + r) * FDIM + g * 8;
    bSrc[I] = pbf + (size_t)(N0 + r) * FDIM + g * 8;
    ldsOff[I] = (I * 256 + w * 64) * 8;   // wave-uniform base (ushort elems)
  }

  floatx4 acc[4][4] = {};

  for (int s = 0; s < NSTEP; ++s) {
    __syncthreads();  // previous iteration's ds_reads complete before overwrite
    #pragma unroll
    for (int I = 0; I < 4; ++I) async16(aSrc[I] + s * BK, &lds_a[ldsOff[I]]);
    #pragma unroll
    for (int I = 0; I < 4; ++I) async16(bSrc[I] + s * BK, &lds_b[ldsOff[I]]);
    __syncthreads();  // drains vmcnt -> staged data visible

    #pragma unroll
    for (int kk = 0; kk < 2; ++kk) {   // two K=32 MFMA windows per BK=64
      const int slot = ((kk * 4 + q) ^ sx) * 8;      // swizzled 16B chunk
      const int aoff = (wr * 64 + lm) * BK + slot;
      const int boff = (wc * 64 + lm) * BK + slot;
      bf16x8 af[4], bfr[4];
      #pragma unroll
      for (int i = 0; i < 4; ++i) af[i]  = *(const bf16x8*)&lds_a[aoff + i * 16 * BK];
      #pragma unroll
      for (int j = 0; j < 4; ++j) bfr[j] = *(const bf16x8*)&lds_b[boff + j * 16 * BK];
      #pragma unroll
      for (int i = 0; i < 4; ++i)
        #pragma unroll
        for (int j = 0; j < 4; ++j)
          acc[i][j] = __builtin_amdgcn_mfma_f32_16x16x32_bf16(af[i], bfr[j], acc[i][j], 0, 0, 0);
    }
  }

  // ---- Epilogue ----
  // C/D layout (16x16x32): col = lane&15, row = (lane>>4)*4 + reg.
  __syncthreads();  // all waves done with staging LDS; reuse it for transpose

  // Per-wave transpose region: 16 rows x 68 floats (pad 64->68 breaks the
  // power-of-2 stride). 1088 floats = 4352 B per wave; waves 0,1 in lds_a,
  // waves 2,3 in lds_b (per-wave disjoint -> no barrier needed; DS pipeline
  // is in-order per wave so write->read needs only compiler lgkmcnt).
  float* wbase = (w < 2) ? ((float*)lds_a + w * 1088)
                         : ((float*)lds_b + (w - 2) * 1088);

  float p2r[4];
  #pragma unroll
  for (int j = 0; j < 4; ++j) p2r[j] = p2[N0 + wc * 64 + j * 16 + lm];
  float x2r[16];
  #pragma unroll
  for (int i = 0; i < 4; ++i)
    #pragma unroll
    for (int v = 0; v < 4; ++v)
      x2r[i * 4 + v] = x2[M0 + wr * 64 + i * 16 + q * 4 + v];

  #pragma unroll
  for (int i = 0; i < 4; ++i) {
    // scatter this 16x64 chunk into LDS (bank: 2-way alias = free)
    #pragma unroll
    for (int j = 0; j < 4; ++j)
      #pragma unroll
      for (int v = 0; v < 4; ++v) {
        float d2 = fmaxf(x2r[i * 4 + v] + p2r[j] - 2.0f * acc[i][j][v], 0.0f);
        wbase[(q * 4 + v) * 68 + j * 16 + lm] = __expf(-0.5f * sqrtf(d2));
      }
    // read back row-major (float4) and store coalesced: per instruction,
    // 4 rows x 256 B contiguous.
    const int mbase = M0 + wr * 64 + i * 16;
    #pragma unroll
    for (int tt = 0; tt < 4; ++tt) {
      const int r2 = q + tt * 4;                         // row within chunk
      const float4 vv = *(const float4*)&wbase[r2 * 68 + lm * 4];
      *(float4*)(out + (size_t)(mbase + r2) * P_ROWS + N0 + wc * 64 + lm * 4) = vv;
    }
  }
}

// ---------------------------------------------------------------------------
extern "C" void kernel_launch(void* const* d_in, const int* in_sizes, int n_in,
                              void* d_out, int out_size, void* d_ws, size_t ws_size,
                              hipStream_t stream) {
  const float* x = (const float*)d_in[0];
  const float* p = (const float*)d_in[1];
  float* out = (float*)d_out;

  // ws layout: xbf (4 MiB) | pbf (4 MiB) | x2 (32 KiB) | p2 (32 KiB)
  char* ws = (char*)d_ws;
  unsigned short* xbf = (unsigned short*)ws;
  unsigned short* pbf = (unsigned short*)(ws + (size_t)B_ROWS * FDIM * 2);
  float* x2 = (float*)(ws + (size_t)(B_ROWS + P_ROWS) * FDIM * 2);
  float* p2 = x2 + B_ROWS;

  prep_kernel<<<dim3((B_ROWS + P_ROWS) / 4), dim3(256), 0, stream>>>(x, p, xbf, pbf, x2, p2);

  gauss_kernel<<<dim3(64 * 64), dim3(256), 0, stream>>>(xbf, pbf, x2, p2, out);
}